// Round 13
// baseline (97.689 us; speedup 1.0000x reference)
//
#include <hip/hip_runtime.h>
#include <math.h>

// GptOssTopKRouter on MI355X — round 13: wave-private burst staging, no barriers.
//
// r12 counters (MfmaUtil 5.8, VALUBusy 9.6, HBM 1.28 TB/s, all pipes idle)
// showed barrier duty-cycle strangled delivered BW. This round keeps r12's
// burst idea (contiguous 256B-per-row load instructions) but drops ALL
// barriers: each wave stages its OWN 32-row x 64-float chunk into a private
// single-buffered LDS tile (within-wave DS ops are in-order, so reads of
// chunk c are issued before writes of chunk c+1 -> no hazard), with the next
// chunk's 8 KB held in registers -> ~8 KB continuously in flight per wave,
// 128 KB/CU.
//
// Compute (verified r7-r12): logits^T = W[32,2880] @ X^T, 6 bf16 MFMA passes
// of 3-term trunc split (hh,mh,lh,hm,mm,hl; logit err ~2e-7, tie-safe).
// 32x32x16 MFMA; W pre-split fragment-packed (d_ws, L2-resident, K padded
// 180->192 with zeros; X addr clamped for pad region -> x0 weight).
// Block = 512 thr = 8 waves = 8 K-eighths x 32 tokens; grid 512 -> 2
// blocks/CU = 4 waves/SIMD. LDS tile row stride 68 floats: bank-uniform
// (zero excess conflict) for both 4-rows-per-instr writes and column reads.

#define HIDDEN 2880
#define NE 32
#define TOPK 4
#define TPB 32            // tokens per block
#define NK16 192          // padded k16 steps (180 real + 12 zero)
#define RK16 180
#define VS (NK16 * 512)   // ver stride in wb: 98304 shorts
#define ROWF 68           // LDS row stride in floats (16B-aligned, bank-uniform)
#define NCHW 6            // chunks per wave (6 x 64 floats = 384 = padded K-eighth)

typedef __attribute__((ext_vector_type(8)))  short bf16x8;
typedef __attribute__((ext_vector_type(16))) float f32x16;

#define MFMA32(a, b, c) __builtin_amdgcn_mfma_f32_32x32x16_bf16((a), (b), (c), 0, 0, 0)

// Pre-kernel: W[32][2880] fp32 -> WB[3 ver][192 ks][512] bf16, exact 32x32
// A-fragment order: elem (l,j) = split_ver(W[l&31][ks*16 + (l>>5)*8 + j]);
// ks >= 180 slots are zero.
__global__ void wb_kernel(const float* __restrict__ w, unsigned short* __restrict__ wb) {
    int i = blockIdx.x * 256 + threadIdx.x;
    if (i >= 3 * VS) return;
    int j = i & 7;
    int l = (i >> 3) & 63;
    int rest = i >> 9;
    int ks  = rest % NK16;
    int ver = rest / NK16;
    unsigned short outv = 0;
    if (ks < RK16) {
        int e = l & 31;
        int k = ks * 16 + (l >> 5) * 8 + j;
        float v = w[e * HIDDEN + k];
        unsigned u = __float_as_uint(v);
        unsigned h = u >> 16;
        float r = v - __uint_as_float(u & 0xffff0000u);          // exact
        unsigned ur = __float_as_uint(r);
        unsigned m = ur >> 16;
        float r2 = r - __uint_as_float(ur & 0xffff0000u);        // exact
        unsigned lo = __float_as_uint(r2) >> 16;
        outv = (unsigned short)(ver == 0 ? h : (ver == 1 ? m : lo));
    }
    wb[i] = outv;
}

// split 8 consecutive fp32 -> 3 bf16x8 (hi, mid, lo), fully in-register
__device__ __forceinline__ void split24(float4 a, float4 b,
                                        bf16x8& H, bf16x8& M, bf16x8& L) {
    union { bf16x8 v; unsigned u[4]; } h, m, l;
    float f[8] = {a.x, a.y, a.z, a.w, b.x, b.y, b.z, b.w};
    unsigned hh[8], mm[8], ll[8];
#pragma unroll
    for (int i = 0; i < 8; ++i) {
        unsigned u = __float_as_uint(f[i]);
        hh[i] = u >> 16;
        float r = f[i] - __uint_as_float(u & 0xffff0000u);       // exact
        unsigned ur = __float_as_uint(r);
        mm[i] = ur >> 16;
        float r2 = r - __uint_as_float(ur & 0xffff0000u);        // exact
        ll[i] = __float_as_uint(r2) >> 16;
    }
#pragma unroll
    for (int i = 0; i < 4; ++i) {
        h.u[i] = hh[2 * i] | (hh[2 * i + 1] << 16);
        m.u[i] = mm[2 * i] | (mm[2 * i + 1] << 16);
        l.u[i] = ll[2 * i] | (ll[2 * i + 1] << 16);
    }
    H = h.v; M = m.v; L = l.v;
}

__global__ __launch_bounds__(512, 4)
void router_kernel(const float* __restrict__ x,
                   const unsigned short* __restrict__ wb,
                   const float* __restrict__ bias,
                   float* __restrict__ out_scores,
                   float* __restrict__ out_idx)
{
    __shared__ float pool[8 * TPB * ROWF];    // 69.6 KB; per-wave tiles; epilogue overlays

    const int tid  = threadIdx.x;
    const int lane = tid & 63;
    const int w    = tid >> 6;        // K-eighth 0..7
    const int col  = lane & 31;       // token (= B-frag col)
    const int kg   = lane >> 5;       // frag k group
    const int tok0 = blockIdx.x * TPB;

    float* tile = pool + w * (TPB * ROWF);    // this wave's private chunk tile

    // ---- staging geometry: instr i covers rows 4i..4i+3, each row a
    //      CONTIGUOUS 256B burst (16 float4 slots across 16 lanes) ----
    const int srow  = lane >> 4;              // 0..3 row-sub within instr
    const int sslot = lane & 15;              // float4 slot within chunk
    const float* xsrc = x + (size_t)(tok0 + srow) * HIDDEN;   // + 4i rows per instr
    float* sdst = tile + srow * ROWF + sslot * 4;             // + 4i*ROWF per instr

    const unsigned short* wk = wb + lane * 8;

    f32x16 acc = {0.f};

#define GLOAD(g, c) do { _Pragma("unroll")                                        \
    for (int i_ = 0; i_ < 8; ++i_) {                                              \
        int ko_ = min(384 * w + 64 * (c) + sslot * 4, HIDDEN - 4);                \
        g[i_] = *(const float4*)(xsrc + (size_t)(4 * i_) * HIDDEN + ko_);         \
    }                                                                             \
} while (0)

#define SWRITE(g) do { _Pragma("unroll")                                          \
    for (int i_ = 0; i_ < 8; ++i_)                                                \
        *(float4*)(sdst + 4 * i_ * ROWF) = g[i_];                                 \
} while (0)

#define MFMA6(WH, WM, WL, XH, XM, XL) do {                                        \
    acc = MFMA32(WH, XH, acc);                                                    \
    acc = MFMA32(WM, XH, acc);                                                    \
    acc = MFMA32(WL, XH, acc);                                                    \
    acc = MFMA32(WH, XM, acc);                                                    \
    acc = MFMA32(WM, XM, acc);                                                    \
    acc = MFMA32(WH, XL, acc);                                                    \
} while (0)

// step s of chunk c: 2 ds_read_b128 (col slice) + 3 W dwordx4 + split + 6 MFMA
#define STEP(c, s) do {                                                           \
    const int ro_ = col * ROWF + (s) * 16 + kg * 8;                               \
    float4 a0_ = *(const float4*)(tile + ro_);                                    \
    float4 a1_ = *(const float4*)(tile + ro_ + 4);                                \
    const unsigned short* p_ = wk + (size_t)(24 * w + 4 * (c) + (s)) * 512;       \
    bf16x8 Wh_ = *(const bf16x8*)(p_);                                            \
    bf16x8 Wm_ = *(const bf16x8*)(p_ + VS);                                       \
    bf16x8 Wl_ = *(const bf16x8*)(p_ + 2 * VS);                                   \
    bf16x8 xh_, xm_, xl_;                                                         \
    split24(a0_, a1_, xh_, xm_, xl_);                                             \
    MFMA6(Wh_, Wm_, Wl_, xh_, xm_, xl_);                                          \
} while (0)

    float4 g[8];                      // next-chunk register buffer (32 VGPR)

    GLOAD(g, 0);
    SWRITE(g);                        // chunk 0 -> LDS (implicit counted vmcnt)
    GLOAD(g, 1);                      // chunk 1 in flight during chunk-0 compute

#pragma unroll 1
    for (int c = 0; c < NCHW; ++c) {
#pragma unroll
        for (int s = 0; s < 4; ++s) STEP(c, s);
        if (c < NCHW - 1) {
            SWRITE(g);                // in-order DS: issued after this chunk's reads
            if (c < NCHW - 2) GLOAD(g, c + 2);
        }
    }

#undef GLOAD
#undef SWRITE
#undef MFMA6
#undef STEP

    __syncthreads();                  // before overlaying pool with epilogue data

    // ---- C/D layout (m74/m101-verified 32x32): col=lane&31=token,
    //      row=(reg&3)+8*(reg>>2)+4*kg = expert ----
    float (*part)[TPB][36] = (float (*)[TPB][36])pool;        // 9216 floats
    float (*score)[33]     = (float (*)[33])(pool + 8 * TPB * 36);

#pragma unroll
    for (int r = 0; r < 16; ++r)
        part[w][col][(r & 3) + 8 * (r >> 2) + 4 * kg] = acc[r];
    __syncthreads();

    // ---- top-4 + softmax, one lane per token ----
    if (tid < TPB) {
        float lg[NE];
#pragma unroll
        for (int e = 0; e < NE; ++e) {
            float s = bias[e];
#pragma unroll
            for (int p = 0; p < 8; ++p) s += part[p][tid][e];
            lg[e] = s;
        }

        float vals[TOPK]; int idxs[TOPK]; unsigned chosen = 0u;
#pragma unroll
        for (int k = 0; k < TOPK; ++k) {
            float m = -INFINITY; int mi = 0;
#pragma unroll
            for (int e = 0; e < NE; ++e) {
                const bool take = (((chosen >> e) & 1u) == 0u) && (lg[e] > m);
                m  = take ? lg[e] : m;
                mi = take ? e : mi;
            }
            vals[k] = m; idxs[k] = mi; chosen |= (1u << (unsigned)mi);
        }
        const float mx = vals[0];
        float p[TOPK]; float sum = 0.f;
#pragma unroll
        for (int k = 0; k < TOPK; ++k) { p[k] = __expf(vals[k] - mx); sum += p[k]; }
        const float inv = 1.0f / sum;
#pragma unroll
        for (int e = 0; e < NE; ++e) {
            float v = 0.f;
#pragma unroll
            for (int k = 0; k < TOPK; ++k) v = (e == idxs[k]) ? p[k] * inv : v;
            score[tid][e] = v;
        }
        const int t = blockIdx.x * TPB + tid;
        float4 iv = make_float4((float)idxs[0], (float)idxs[1], (float)idxs[2], (float)idxs[3]);
        *reinterpret_cast<float4*>(out_idx + (size_t)t * TOPK) = iv;
    }
    __syncthreads();

    // ---- coalesced score store: 1024 floats, 512 threads x float2 ----
    {
        const int f = tid * 2;
        const int t = f >> 5, e = f & 31;
        float2 v = make_float2(score[t][e], score[t][e + 1]);
        *reinterpret_cast<float2*>(out_scores + (size_t)blockIdx.x * TPB * NE + f) = v;
    }
}

extern "C" void kernel_launch(void* const* d_in, const int* in_sizes, int n_in,
                              void* d_out, int out_size, void* d_ws, size_t ws_size,
                              hipStream_t stream)
{
    const float* x = (const float*)d_in[0];
    const float* w = (const float*)d_in[1];
    const float* b = (const float*)d_in[2];
    const int T = in_sizes[0] / HIDDEN;            // 16384 tokens

    unsigned short* wbuf = (unsigned short*)d_ws;  // 3*192*512 bf16 = 590 KB
    float* out        = (float*)d_out;
    float* out_scores = out;                       // [T, 32]
    float* out_idx    = out + (size_t)T * NE;      // [T, 4] as fp32 values

    wb_kernel<<<dim3((3 * VS + 255) / 256), dim3(256), 0, stream>>>(w, wbuf);
    router_kernel<<<dim3(T / TPB), dim3(512), 0, stream>>>(x, wbuf, b, out_scores, out_idx);
}